// Round 18
// baseline (1141.643 us; speedup 1.0000x reference)
//
#include <hip/hip_runtime.h>
#include <hip/hip_fp16.h>

#define N_NODES 100000
#define N_EDGES 1600000
#define NUM_G   4096
#define HID     128
#define F_IN    11
#define F_PAD   16
#define F_OUT   19

#define NB      256                  // dst buckets
#define KPB     391                  // nodes per bucket: 256*391 = 100096 >= 100000
#define BCAP    8192                 // padded capacity per bucket (max count ~6600)
#define GCAP    1024                 // padded ewp capacity per graph (max ~790)
#define P01_EPB 2048                 // edges per block in P1
#define NREG    8                    // src regions (XCD shards)
#define REGW    12500                // nodes per region
#define GPB     4                    // graphs per pool_gather block (8 groups/graph)
#define NAGG    782                  // agg blocks in fused agg_es8 = ceil(100000/128)
#define NGSET   (NUM_G / GPB)        // 1024

// ---------------- helpers ----------------
__device__ inline void acc_row_f16(float* acc, uint4 u, float w) {
    const __half2* hp = (const __half2*)&u;
#pragma unroll
    for (int i = 0; i < 4; ++i) {
        acc[2 * i]     += __half2float(__low2half(hp[i]))  * w;
        acc[2 * i + 1] += __half2float(__high2half(hp[i])) * w;
    }
}
__device__ inline void add_row_f16(float* acc, uint4 u) {
    const __half2* hp = (const __half2*)&u;
#pragma unroll
    for (int i = 0; i < 4; ++i) {
        acc[2 * i]     += __half2float(__low2half(hp[i]));
        acc[2 * i + 1] += __half2float(__high2half(hp[i]));
    }
}

// ---------------- P1: single-pass scatter (src<<9|dstLocal) into PADDED bucket regions --
__global__ void p1_place(const int* __restrict__ src, const int* __restrict__ dst,
                         int* __restrict__ bcur, unsigned int* __restrict__ ebuf) {
    __shared__ int h[NB];
    __shared__ int base[NB];
    h[threadIdx.x] = 0;
    __syncthreads();
    unsigned int pk[8]; int bn[8];
    int b0 = blockIdx.x * P01_EPB;
    int e8 = b0 + threadIdx.x * 8;
    if (e8 + 8 <= N_EDGES) {
        int4 s0 = *(const int4*)(src + e8);
        int4 s1 = *(const int4*)(src + e8 + 4);
        int4 d0 = *(const int4*)(dst + e8);
        int4 d1 = *(const int4*)(dst + e8 + 4);
        int ss[8] = { s0.x, s0.y, s0.z, s0.w, s1.x, s1.y, s1.z, s1.w };
        int dd[8] = { d0.x, d0.y, d0.z, d0.w, d1.x, d1.y, d1.z, d1.w };
#pragma unroll
        for (int k = 0; k < 8; ++k) {
            bn[k] = dd[k] / KPB;
            pk[k] = ((unsigned)ss[k] << 9) | (unsigned)(dd[k] - bn[k] * KPB);
        }
    } else {
#pragma unroll
        for (int k = 0; k < 8; ++k) {
            int e = e8 + k;
            if (e < N_EDGES) {
                int d = dst[e];
                bn[k] = d / KPB;
                pk[k] = ((unsigned)src[e] << 9) | (unsigned)(d - bn[k] * KPB);
            } else bn[k] = -1;
        }
    }
#pragma unroll
    for (int k = 0; k < 8; ++k)
        if (bn[k] >= 0) atomicAdd(&h[bn[k]], 1);
    __syncthreads();
    {
        int c = h[threadIdx.x];
        base[threadIdx.x] = c ? atomicAdd(&bcur[threadIdx.x], c) : 0;
    }
    __syncthreads();
    h[threadIdx.x] = 0;
    __syncthreads();
#pragma unroll
    for (int k = 0; k < 8; ++k) {
        if (bn[k] >= 0) {
            int r = atomicAdd(&h[bn[k]], 1);
            ebuf[(size_t)bn[k] * BCAP + base[bn[k]] + r] = pk[k];
        }
    }
}

// ---------------- P2: per-bucket CSR(padded) build + deg + dinv + wd + xp(f16) ----------
// scan via wave-shuffle (2 barriers instead of 18)
__global__ void p2_build(const unsigned int* __restrict__ ebuf, const int* __restrict__ bcur,
                         const float* __restrict__ x,
                         int* __restrict__ row_ptr, int* __restrict__ deg,
                         int* __restrict__ col, float* __restrict__ wd,
                         float* __restrict__ dinv, __half* __restrict__ xp) {
    __shared__ int hist[512];
    __shared__ float ldinv[512];
    __shared__ int wsum[8];
    __shared__ int woff[8];
    int b  = blockIdx.x;
    int t  = threadIdx.x;
    int dbase = b * KPB;
    int nd = N_NODES - dbase; if (nd > KPB) nd = KPB;
    hist[t] = 0;
    __syncthreads();
    int e0 = b * BCAP;
    int e1 = e0 + bcur[b];
    for (int e = e0 + t; e < e1; e += 512)
        atomicAdd(&hist[ebuf[e] & 511u], 1);
    __syncthreads();
    int v = hist[t];
    // wave-level inclusive scan (64 lanes, no barriers)
    int lane = t & 63, wv = t >> 6;
    int sv = v;
#pragma unroll
    for (int off = 1; off < 64; off <<= 1) {
        int n = __shfl_up(sv, off, 64);
        if (lane >= off) sv += n;
    }
    if (lane == 63) wsum[wv] = sv;
    __syncthreads();
    if (t == 0) {
        int run = 0;
#pragma unroll
        for (int w = 0; w < 8; ++w) { woff[w] = run; run += wsum[w]; }
    }
    __syncthreads();
    int excl = sv - v + woff[wv];
    float di = rsqrtf(1.0f + (float)v);
    ldinv[t] = di;
    if (t < nd) {
        row_ptr[dbase + t] = e0 + excl;
        deg[dbase + t]     = v;
        dinv[dbase + t]    = di;
    }
    __syncthreads();
    hist[t] = e0 + excl;           // reuse as col-position cursor
    __syncthreads();
    for (int e = e0 + t; e < e1; e += 512) {
        unsigned int w = ebuf[e];
        int dl = (int)(w & 511u);
        int pos = atomicAdd(&hist[dl], 1);
        col[pos] = (int)(w >> 9);
        wd[pos]  = ldinv[dl];      // dinv[dst] per edge
    }
    // fused prep: xp[v][0..15] = f16(dinv[v]*x[v][f]) (pad 11->16)
    for (int idx = t; idx < nd * F_PAD; idx += 512) {
        int vl = idx >> 4, f = idx & 15;
        int gv = dbase + vl;
        xp[(size_t)gv * F_PAD + f] =
            __float2half_rn((f < F_IN) ? ldinv[vl] * x[(size_t)gv * F_IN + f] : 0.f);
    }
}

// ---------------- fused agg_gemm1 + edge_sort8 (independent phases, one launch) ---------
__global__ void agg_es8(const __half* __restrict__ xp, const int* __restrict__ row_ptr,
                        const int* __restrict__ deg, const int* __restrict__ col,
                        const float* __restrict__ dinv,
                        const float* __restrict__ W1, const float* __restrict__ b1,
                        __half* __restrict__ Bh,
                        const int* __restrict__ batch, const float* __restrict__ wd,
                        uint2* __restrict__ ewp, int* __restrict__ gro,
                        int* __restrict__ gb) {
    __shared__ float xs[128][F_PAD];       // 8 KB  (agg path)
    __shared__ float W1s[F_IN * HID];      // 5.5 KB
    __shared__ float b1s[HID];
    __shared__ float ds[128];
    __shared__ int cnt[NREG];              // (sort path)
    __shared__ int cur[NREG];
    __shared__ int range[2];
    int tid = threadIdx.x;

    if (blockIdx.x < NAGG) {
        // ---------------- agg_gemm1 body ----------------
        for (int i = tid; i < F_IN * HID; i += 256) W1s[i] = W1[i];
        if (tid < HID) b1s[tid] = b1[tid];
        const uint4* xp4 = (const uint4*)xp;   // row = 2 uint4 (8 halves each)
        int v0   = blockIdx.x * 128;
        int v    = v0 + (tid >> 1);
        int lane = tid & 1;                    // lane owns 8 feats
        if (v < N_NODES) {
            if (lane == 0) ds[tid >> 1] = dinv[v];
            float a[8];
#pragma unroll
            for (int k = 0; k < 8; ++k) a[k] = 0.f;
            add_row_f16(a, xp4[(size_t)v * 2 + lane]);         // self-loop
            int j = row_ptr[v], end = j + deg[v];
            for (; j + 3 < end; j += 4) {
                int s0 = col[j], s1 = col[j + 1], s2 = col[j + 2], s3 = col[j + 3];
                uint4 u0 = xp4[(size_t)s0 * 2 + lane];
                uint4 u1 = xp4[(size_t)s1 * 2 + lane];
                uint4 u2 = xp4[(size_t)s2 * 2 + lane];
                uint4 u3 = xp4[(size_t)s3 * 2 + lane];
                add_row_f16(a, u0); add_row_f16(a, u1);
                add_row_f16(a, u2); add_row_f16(a, u3);
            }
            for (; j < end; ++j)
                add_row_f16(a, xp4[(size_t)col[j] * 2 + lane]);
#pragma unroll
            for (int k = 0; k < 8; ++k) xs[tid >> 1][lane * 8 + k] = a[k];
        }
        __syncthreads();
        int jf   = tid & 127;
        int half = tid >> 7;
        int nmax = N_NODES - v0; if (nmax > 128) nmax = 128;
        for (int n = half; n < nmax; n += 2) {
            float a = 0.f;
#pragma unroll
            for (int k = 0; k < F_IN; ++k) a += xs[n][k] * W1s[k * HID + jf];
            float dv = ds[n];
            float h = fmaxf(dv * a + b1s[jf], 0.f);
            Bh[(size_t)(v0 + n) * HID + jf] = __float2half_rn(dv * h);
        }
    } else {
        // ---------------- edge_sort8 body (padded row_ptr: per-bucket sub-ranges) -------
        int g = blockIdx.x - NAGG;
        if (tid < NREG) cnt[tid] = 0;
        if (tid < 2) {                     // lower_bound(batch, g) / (batch, g+1)
            int tgt = g + tid;
            int lo = 0, hi = N_NODES;
            while (lo < hi) { int m = (lo + hi) >> 1; if (batch[m] < tgt) lo = m + 1; else hi = m; }
            range[tid] = lo;
        }
        __syncthreads();
        int r0 = range[0], r1 = range[1];
        if (tid == 0) {
            gb[g] = r0;
            if (g == NUM_G - 1) gb[NUM_G] = N_NODES;
        }
        int bb0 = 0, bb1 = -1;
        if (r1 > r0) { bb0 = r0 / KPB; bb1 = (r1 - 1) / KPB; }
        // count phase
        for (int bb = bb0; bb <= bb1; ++bb) {
            int vlo = r0 > bb * KPB ? r0 : bb * KPB;
            int vhi = r1 < bb * KPB + KPB ? r1 : bb * KPB + KPB;
            int ee0 = row_ptr[vlo];
            int ee1 = row_ptr[vhi - 1] + deg[vhi - 1];
            for (int e = ee0 + tid; e < ee1; e += 256)
                atomicAdd(&cnt[(unsigned)col[e] / REGW], 1);
        }
        for (int v = r0 + tid; v < r1; v += 256)
            atomicAdd(&cnt[(unsigned)v / REGW], 1);
        __syncthreads();
        if (tid == 0) {
            int run = g * GCAP;
#pragma unroll
            for (int p = 0; p < NREG; ++p) {
                gro[g * 9 + p] = run;
                cur[p] = run;
                run += cnt[p];
            }
            gro[g * 9 + 8] = run;
        }
        __syncthreads();
        // scatter phase
        for (int bb = bb0; bb <= bb1; ++bb) {
            int vlo = r0 > bb * KPB ? r0 : bb * KPB;
            int vhi = r1 < bb * KPB + KPB ? r1 : bb * KPB + KPB;
            int ee0 = row_ptr[vlo];
            int ee1 = row_ptr[vhi - 1] + deg[vhi - 1];
            for (int e = ee0 + tid; e < ee1; e += 256) {
                int s = col[e];
                int pos = atomicAdd(&cur[(unsigned)s / REGW], 1);
                ewp[pos] = make_uint2((unsigned)s, __float_as_uint(wd[e]));
            }
        }
        for (int v = r0 + tid; v < r1; v += 256) {
            int pos = atomicAdd(&cur[(unsigned)v / REGW], 1);
            ewp[pos] = make_uint2((unsigned)v, __float_as_uint(dinv[v]));
        }
    }
}

// ---------------- pool_gather + fused combine (last-arrival per gset) -------------------
// blockIdx = gset*8 + p -> round-robin XCD mapping keeps region p on XCD p.
__global__ void pool_gather(const __half* __restrict__ Bh,
                            const int* __restrict__ gro,
                            const uint2* __restrict__ ewp,
                            float* __restrict__ part, int* __restrict__ done,
                            const int* __restrict__ gb,
                            const float* __restrict__ W2, const float* __restrict__ b2,
                            const float* __restrict__ Wlin, const float* __restrict__ blin,
                            float* __restrict__ out) {
    __shared__ float red[32][HID + 4];    // 16.9 KB (reused by combine)
    __shared__ int isLast;
    int b    = blockIdx.x;
    int gset = b >> 3;
    int p    = b & 7;
    int tid  = threadIdx.x;
    int grp  = tid >> 3;                  // 0..31
    int lane = tid & 7;                   // owns feats [lane*16, lane*16+16)
    int g    = gset * GPB + (grp >> 3);   // 4 graphs/block
    int q    = grp & 7;                   // eighth
    const uint4* B4 = (const uint4*)Bh;   // row = 16 uint4
    float acc[16];
#pragma unroll
    for (int k = 0; k < 16; ++k) acc[k] = 0.f;

    int e0 = gro[g * 9 + p], e1 = gro[g * 9 + p + 1];
    int e = e0 + q;
    for (; e + 8 < e1; e += 16) {         // 2 entries/iter, 4 row-loads in flight
        uint2 q0 = ewp[e], q1 = ewp[e + 8];
        uint4 u00 = B4[(size_t)q0.x * 16 + lane * 2];
        uint4 u01 = B4[(size_t)q0.x * 16 + lane * 2 + 1];
        uint4 u10 = B4[(size_t)q1.x * 16 + lane * 2];
        uint4 u11 = B4[(size_t)q1.x * 16 + lane * 2 + 1];
        float w0 = __uint_as_float(q0.y), w1 = __uint_as_float(q1.y);
        acc_row_f16(acc,     u00, w0);
        acc_row_f16(acc + 8, u01, w0);
        acc_row_f16(acc,     u10, w1);
        acc_row_f16(acc + 8, u11, w1);
    }
    for (; e < e1; e += 8) {
        uint2 q0 = ewp[e];
        uint4 u00 = B4[(size_t)q0.x * 16 + lane * 2];
        uint4 u01 = B4[(size_t)q0.x * 16 + lane * 2 + 1];
        float w0 = __uint_as_float(q0.y);
        acc_row_f16(acc,     u00, w0);
        acc_row_f16(acc + 8, u01, w0);
    }
#pragma unroll
    for (int k = 0; k < 16; ++k) red[grp][lane * 16 + k] = acc[k];
    __syncthreads();
    // combine 8 groups per graph, write 4 part rows
    for (int i = tid; i < GPB * HID; i += 256) {
        int gg = i >> 7, f = i & 127;
        int rb = gg * 8;
        float s = 0.f;
#pragma unroll
        for (int r = 0; r < 8; ++r) s += red[rb + r][f];
        part[(size_t)((gset * GPB + gg) * NREG + p) * HID + f] = s;
    }
    __syncthreads();
    if (tid == 0) {
        __threadfence();                          // release part writes
        int old = atomicAdd(&done[gset], 1);
        isLast = (old == NREG - 1);
    }
    __syncthreads();
    if (!isLast) return;
    __threadfence();                              // acquire other blocks' part writes

    // ---- combine + mean + W2 + b2 + Wlin + blin for the gset's 4 graphs ----
    int half = tid >> 7;                          // 2 graphs at a time
    int f    = tid & 127;
    for (int gpair = 0; gpair < GPB; gpair += 2) {
        int gg = gset * GPB + gpair + half;
        float s = 0.f;
#pragma unroll
        for (int pp = 0; pp < NREG; ++pp)
            s += part[(size_t)(gg * NREG + pp) * HID + f];
        int cntv = gb[gg + 1] - gb[gg];
        float inv = (cntv > 0) ? 1.0f / (float)cntv : 0.f;
        red[half][f] = s * inv;
        __syncthreads();
        float bs = (cntv > 0) ? 1.0f : 0.f;
        float tj = b2[f] * bs;
#pragma unroll 8
        for (int k = 0; k < HID; ++k) tj += red[half][k] * W2[k * HID + f];
        red[2 + half][f] = tj;
        __syncthreads();
        if (f < F_OUT) {
            float o = blin[f];
#pragma unroll 8
            for (int k = 0; k < HID; ++k) o += red[2 + half][k] * Wlin[k * F_OUT + f];
            out[(size_t)gg * F_OUT + f] = o;
        }
        __syncthreads();
    }
}

extern "C" void kernel_launch(void* const* d_in, const int* in_sizes, int n_in,
                              void* d_out, int out_size, void* d_ws, size_t ws_size,
                              hipStream_t stream) {
    const float* x    = (const float*)d_in[0];
    const int*   esrc = (const int*)  d_in[1];
    const int*   edst = (const int*)  d_in[2];
    const int*   batch= (const int*)  d_in[3];
    const float* W1   = (const float*)d_in[4];
    const float* b1   = (const float*)d_in[5];
    const float* W2   = (const float*)d_in[6];
    const float* b2   = (const float*)d_in[7];
    const float* Wlin = (const float*)d_in[8];
    const float* blin = (const float*)d_in[9];
    float* out = (float*)d_out;

    // workspace layout (~106 MB), 16B-aligned segments
    char* p = (char*)d_ws;
    float*        dinv    = (float*)p;        p += sizeof(float) * N_NODES;
    __half*       xp      = (__half*)p;       p += sizeof(__half) * (size_t)N_NODES * F_PAD;
    __half*       Bh      = (__half*)p;       p += sizeof(__half) * (size_t)N_NODES * HID;
    unsigned int* ebuf    = (unsigned int*)p; p += sizeof(unsigned int) * (size_t)NB * BCAP;
    int*          col     = (int*)p;          p += sizeof(int) * (size_t)NB * BCAP;
    float*        wd      = (float*)p;        p += sizeof(float) * (size_t)NB * BCAP;
    int*          deg     = (int*)p;          p += sizeof(int) * N_NODES;
    uint2*        ewp     = (uint2*)p;        p += sizeof(uint2) * (size_t)NUM_G * GCAP;
    float*        part    = (float*)p;        p += sizeof(float) * (size_t)NUM_G * NREG * HID;
    int*          row_ptr = (int*)p;          p += sizeof(int) * (N_NODES + 4);
    int*          gb      = (int*)p;          p += sizeof(int) * (NUM_G + 4);
    int*          gro     = (int*)p;          p += sizeof(int) * (NUM_G * 9 + 4);
    int*          bcur    = (int*)p;          p += sizeof(int) * NB;     // bcur + done
    int*          done    = (int*)p;          p += sizeof(int) * NGSET;  // contiguous

    const int nblk_e = (N_EDGES + P01_EPB - 1) / P01_EPB;   // 782

    // ---- zero bcur + done in one memset; single-pass padded counting sort ----
    hipMemsetAsync(bcur, 0, sizeof(int) * (NB + NGSET), stream);
    p1_place<<<nblk_e, 256, 0, stream>>>(esrc, edst, bcur, ebuf);
    p2_build<<<NB, 512, 0, stream>>>(ebuf, bcur, x, row_ptr, deg, col, wd, dinv, xp);

    // ---- fused: layer-1 aggregate + W1-GEMM (blocks 0..781)
    //            + per-graph region sort (blocks 782..4877) — independent, co-scheduled
    agg_es8<<<NAGG + NUM_G, 256, 0, stream>>>(xp, row_ptr, deg, col, dinv, W1, b1, Bh,
                                              batch, wd, ewp, gro, gb);

    // ---- XCD-sharded layer-2 aggregate + pool partials + fused combine/head ----
    pool_gather<<<NGSET * NREG, 256, 0, stream>>>(Bh, gro, ewp, part, done, gb,
                                                  W2, b2, Wlin, blin, out);
}

// Round 19
// 232.642 us; speedup vs baseline: 4.9073x; 4.9073x over previous
//
#include <hip/hip_runtime.h>
#include <hip/hip_fp16.h>

#define N_NODES 100000
#define N_EDGES 1600000
#define NUM_G   4096
#define HID     128
#define F_IN    11
#define F_PAD   16
#define F_OUT   19

#define NB      256                  // dst buckets
#define KPB     391                  // nodes per bucket: 256*391 = 100096 >= 100000
#define BCAP    8192                 // padded capacity per bucket (max count ~6600)
#define GCAP    1024                 // padded ewp capacity per graph (max ~790)
#define P01_EPB 2048                 // edges per block in P1
#define NREG    8                    // src regions (XCD shards)
#define REGW    12500                // nodes per region
#define GPB     4                    // graphs per pool_gather block (8 groups/graph)
#define NAGG    782                  // agg blocks in fused agg_es8 = ceil(100000/128)

// ---------------- helpers ----------------
__device__ inline void acc_row_f16(float* acc, uint4 u, float w) {
    const __half2* hp = (const __half2*)&u;
#pragma unroll
    for (int i = 0; i < 4; ++i) {
        acc[2 * i]     += __half2float(__low2half(hp[i]))  * w;
        acc[2 * i + 1] += __half2float(__high2half(hp[i])) * w;
    }
}
__device__ inline void add_row_f16(float* acc, uint4 u) {
    const __half2* hp = (const __half2*)&u;
#pragma unroll
    for (int i = 0; i < 4; ++i) {
        acc[2 * i]     += __half2float(__low2half(hp[i]));
        acc[2 * i + 1] += __half2float(__high2half(hp[i]));
    }
}

// ---------------- P1: single-pass scatter (src<<9|dstLocal) into PADDED bucket regions --
__global__ void p1_place(const int* __restrict__ src, const int* __restrict__ dst,
                         int* __restrict__ bcur, unsigned int* __restrict__ ebuf) {
    __shared__ int h[NB];
    __shared__ int base[NB];
    h[threadIdx.x] = 0;
    __syncthreads();
    unsigned int pk[8]; int bn[8];
    int b0 = blockIdx.x * P01_EPB;
    int e8 = b0 + threadIdx.x * 8;
    if (e8 + 8 <= N_EDGES) {
        int4 s0 = *(const int4*)(src + e8);
        int4 s1 = *(const int4*)(src + e8 + 4);
        int4 d0 = *(const int4*)(dst + e8);
        int4 d1 = *(const int4*)(dst + e8 + 4);
        int ss[8] = { s0.x, s0.y, s0.z, s0.w, s1.x, s1.y, s1.z, s1.w };
        int dd[8] = { d0.x, d0.y, d0.z, d0.w, d1.x, d1.y, d1.z, d1.w };
#pragma unroll
        for (int k = 0; k < 8; ++k) {
            bn[k] = dd[k] / KPB;
            pk[k] = ((unsigned)ss[k] << 9) | (unsigned)(dd[k] - bn[k] * KPB);
        }
    } else {
#pragma unroll
        for (int k = 0; k < 8; ++k) {
            int e = e8 + k;
            if (e < N_EDGES) {
                int d = dst[e];
                bn[k] = d / KPB;
                pk[k] = ((unsigned)src[e] << 9) | (unsigned)(d - bn[k] * KPB);
            } else bn[k] = -1;
        }
    }
#pragma unroll
    for (int k = 0; k < 8; ++k)
        if (bn[k] >= 0) atomicAdd(&h[bn[k]], 1);
    __syncthreads();
    {
        int c = h[threadIdx.x];
        base[threadIdx.x] = c ? atomicAdd(&bcur[threadIdx.x], c) : 0;
    }
    __syncthreads();
    h[threadIdx.x] = 0;
    __syncthreads();
#pragma unroll
    for (int k = 0; k < 8; ++k) {
        if (bn[k] >= 0) {
            int r = atomicAdd(&h[bn[k]], 1);
            ebuf[(size_t)bn[k] * BCAP + base[bn[k]] + r] = pk[k];
        }
    }
}

// ---------------- P2: per-bucket CSR(padded) build + deg + dinv + wd + xp(f16) ----------
// scan via wave-shuffle (2 barriers instead of 18)
__global__ void p2_build(const unsigned int* __restrict__ ebuf, const int* __restrict__ bcur,
                         const float* __restrict__ x,
                         int* __restrict__ row_ptr, int* __restrict__ deg,
                         int* __restrict__ col, float* __restrict__ wd,
                         float* __restrict__ dinv, __half* __restrict__ xp) {
    __shared__ int hist[512];
    __shared__ float ldinv[512];
    __shared__ int wsum[8];
    __shared__ int woff[8];
    int b  = blockIdx.x;
    int t  = threadIdx.x;
    int dbase = b * KPB;
    int nd = N_NODES - dbase; if (nd > KPB) nd = KPB;
    hist[t] = 0;
    __syncthreads();
    int e0 = b * BCAP;
    int e1 = e0 + bcur[b];
    for (int e = e0 + t; e < e1; e += 512)
        atomicAdd(&hist[ebuf[e] & 511u], 1);
    __syncthreads();
    int v = hist[t];
    // wave-level inclusive scan (64 lanes, no barriers)
    int lane = t & 63, wv = t >> 6;
    int sv = v;
#pragma unroll
    for (int off = 1; off < 64; off <<= 1) {
        int n = __shfl_up(sv, off, 64);
        if (lane >= off) sv += n;
    }
    if (lane == 63) wsum[wv] = sv;
    __syncthreads();
    if (t == 0) {
        int run = 0;
#pragma unroll
        for (int w = 0; w < 8; ++w) { woff[w] = run; run += wsum[w]; }
    }
    __syncthreads();
    int excl = sv - v + woff[wv];
    float di = rsqrtf(1.0f + (float)v);
    ldinv[t] = di;
    if (t < nd) {
        row_ptr[dbase + t] = e0 + excl;
        deg[dbase + t]     = v;
        dinv[dbase + t]    = di;
    }
    __syncthreads();
    hist[t] = e0 + excl;           // reuse as col-position cursor
    __syncthreads();
    for (int e = e0 + t; e < e1; e += 512) {
        unsigned int w = ebuf[e];
        int dl = (int)(w & 511u);
        int pos = atomicAdd(&hist[dl], 1);
        col[pos] = (int)(w >> 9);
        wd[pos]  = ldinv[dl];      // dinv[dst] per edge
    }
    // fused prep: xp[v][0..15] = f16(dinv[v]*x[v][f]) (pad 11->16)
    for (int idx = t; idx < nd * F_PAD; idx += 512) {
        int vl = idx >> 4, f = idx & 15;
        int gv = dbase + vl;
        xp[(size_t)gv * F_PAD + f] =
            __float2half_rn((f < F_IN) ? ldinv[vl] * x[(size_t)gv * F_IN + f] : 0.f);
    }
}

// ---------------- fused agg_gemm1 + edge_sort8 (independent phases, one launch) ---------
__global__ void agg_es8(const __half* __restrict__ xp, const int* __restrict__ row_ptr,
                        const int* __restrict__ deg, const int* __restrict__ col,
                        const float* __restrict__ dinv,
                        const float* __restrict__ W1, const float* __restrict__ b1,
                        __half* __restrict__ Bh,
                        const int* __restrict__ batch, const float* __restrict__ wd,
                        uint2* __restrict__ ewp, int* __restrict__ gro,
                        int* __restrict__ gb) {
    __shared__ float xs[128][F_PAD];       // 8 KB  (agg path)
    __shared__ float W1s[F_IN * HID];      // 5.5 KB
    __shared__ float b1s[HID];
    __shared__ float ds[128];
    __shared__ int cnt[NREG];              // (sort path)
    __shared__ int cur[NREG];
    __shared__ int range[2];
    int tid = threadIdx.x;

    if (blockIdx.x < NAGG) {
        // ---------------- agg_gemm1 body ----------------
        for (int i = tid; i < F_IN * HID; i += 256) W1s[i] = W1[i];
        if (tid < HID) b1s[tid] = b1[tid];
        const uint4* xp4 = (const uint4*)xp;   // row = 2 uint4 (8 halves each)
        int v0   = blockIdx.x * 128;
        int v    = v0 + (tid >> 1);
        int lane = tid & 1;                    // lane owns 8 feats
        if (v < N_NODES) {
            if (lane == 0) ds[tid >> 1] = dinv[v];
            float a[8];
#pragma unroll
            for (int k = 0; k < 8; ++k) a[k] = 0.f;
            add_row_f16(a, xp4[(size_t)v * 2 + lane]);         // self-loop
            int j = row_ptr[v], end = j + deg[v];
            for (; j + 3 < end; j += 4) {
                int s0 = col[j], s1 = col[j + 1], s2 = col[j + 2], s3 = col[j + 3];
                uint4 u0 = xp4[(size_t)s0 * 2 + lane];
                uint4 u1 = xp4[(size_t)s1 * 2 + lane];
                uint4 u2 = xp4[(size_t)s2 * 2 + lane];
                uint4 u3 = xp4[(size_t)s3 * 2 + lane];
                add_row_f16(a, u0); add_row_f16(a, u1);
                add_row_f16(a, u2); add_row_f16(a, u3);
            }
            for (; j < end; ++j)
                add_row_f16(a, xp4[(size_t)col[j] * 2 + lane]);
#pragma unroll
            for (int k = 0; k < 8; ++k) xs[tid >> 1][lane * 8 + k] = a[k];
        }
        __syncthreads();
        int jf   = tid & 127;
        int half = tid >> 7;
        int nmax = N_NODES - v0; if (nmax > 128) nmax = 128;
        for (int n = half; n < nmax; n += 2) {
            float a = 0.f;
#pragma unroll
            for (int k = 0; k < F_IN; ++k) a += xs[n][k] * W1s[k * HID + jf];
            float dv = ds[n];
            float h = fmaxf(dv * a + b1s[jf], 0.f);
            Bh[(size_t)(v0 + n) * HID + jf] = __float2half_rn(dv * h);
        }
    } else {
        // ---------------- edge_sort8 body (padded row_ptr: per-bucket sub-ranges) -------
        int g = blockIdx.x - NAGG;
        if (tid < NREG) cnt[tid] = 0;
        if (tid < 2) {                     // lower_bound(batch, g) / (batch, g+1)
            int tgt = g + tid;
            int lo = 0, hi = N_NODES;
            while (lo < hi) { int m = (lo + hi) >> 1; if (batch[m] < tgt) lo = m + 1; else hi = m; }
            range[tid] = lo;
        }
        __syncthreads();
        int r0 = range[0], r1 = range[1];
        if (tid == 0) {
            gb[g] = r0;
            if (g == NUM_G - 1) gb[NUM_G] = N_NODES;
        }
        int bb0 = 0, bb1 = -1;
        if (r1 > r0) { bb0 = r0 / KPB; bb1 = (r1 - 1) / KPB; }
        // count phase
        for (int bb = bb0; bb <= bb1; ++bb) {
            int vlo = r0 > bb * KPB ? r0 : bb * KPB;
            int vhi = r1 < bb * KPB + KPB ? r1 : bb * KPB + KPB;
            int ee0 = row_ptr[vlo];
            int ee1 = row_ptr[vhi - 1] + deg[vhi - 1];
            for (int e = ee0 + tid; e < ee1; e += 256)
                atomicAdd(&cnt[(unsigned)col[e] / REGW], 1);
        }
        for (int v = r0 + tid; v < r1; v += 256)
            atomicAdd(&cnt[(unsigned)v / REGW], 1);
        __syncthreads();
        if (tid == 0) {
            int run = g * GCAP;
#pragma unroll
            for (int p = 0; p < NREG; ++p) {
                gro[g * 9 + p] = run;
                cur[p] = run;
                run += cnt[p];
            }
            gro[g * 9 + 8] = run;
        }
        __syncthreads();
        // scatter phase
        for (int bb = bb0; bb <= bb1; ++bb) {
            int vlo = r0 > bb * KPB ? r0 : bb * KPB;
            int vhi = r1 < bb * KPB + KPB ? r1 : bb * KPB + KPB;
            int ee0 = row_ptr[vlo];
            int ee1 = row_ptr[vhi - 1] + deg[vhi - 1];
            for (int e = ee0 + tid; e < ee1; e += 256) {
                int s = col[e];
                int pos = atomicAdd(&cur[(unsigned)s / REGW], 1);
                ewp[pos] = make_uint2((unsigned)s, __float_as_uint(wd[e]));
            }
        }
        for (int v = r0 + tid; v < r1; v += 256) {
            int pos = atomicAdd(&cur[(unsigned)v / REGW], 1);
            ewp[pos] = make_uint2((unsigned)v, __float_as_uint(dinv[v]));
        }
    }
}

// ---------------- pool_gather: block (gset,p); 32 groups x 8 lanes; 8 groups/graph ------
// blockIdx = gset*8 + p -> round-robin XCD mapping keeps region p on XCD p.
__global__ void pool_gather(const __half* __restrict__ Bh,
                            const int* __restrict__ gro,
                            const uint2* __restrict__ ewp,
                            float* __restrict__ part) {
    __shared__ float red[32][HID + 4];    // 16.9 KB
    int b    = blockIdx.x;
    int gset = b >> 3;
    int p    = b & 7;
    int tid  = threadIdx.x;
    int grp  = tid >> 3;                  // 0..31
    int lane = tid & 7;                   // owns feats [lane*16, lane*16+16)
    int g    = gset * GPB + (grp >> 3);   // 4 graphs/block
    int q    = grp & 7;                   // eighth
    const uint4* B4 = (const uint4*)Bh;   // row = 16 uint4
    float acc[16];
#pragma unroll
    for (int k = 0; k < 16; ++k) acc[k] = 0.f;

    int e0 = gro[g * 9 + p], e1 = gro[g * 9 + p + 1];
    int e = e0 + q;
    for (; e + 8 < e1; e += 16) {         // 2 entries/iter, 4 row-loads in flight
        uint2 q0 = ewp[e], q1 = ewp[e + 8];
        uint4 u00 = B4[(size_t)q0.x * 16 + lane * 2];
        uint4 u01 = B4[(size_t)q0.x * 16 + lane * 2 + 1];
        uint4 u10 = B4[(size_t)q1.x * 16 + lane * 2];
        uint4 u11 = B4[(size_t)q1.x * 16 + lane * 2 + 1];
        float w0 = __uint_as_float(q0.y), w1 = __uint_as_float(q1.y);
        acc_row_f16(acc,     u00, w0);
        acc_row_f16(acc + 8, u01, w0);
        acc_row_f16(acc,     u10, w1);
        acc_row_f16(acc + 8, u11, w1);
    }
    for (; e < e1; e += 8) {
        uint2 q0 = ewp[e];
        uint4 u00 = B4[(size_t)q0.x * 16 + lane * 2];
        uint4 u01 = B4[(size_t)q0.x * 16 + lane * 2 + 1];
        float w0 = __uint_as_float(q0.y);
        acc_row_f16(acc,     u00, w0);
        acc_row_f16(acc + 8, u01, w0);
    }
#pragma unroll
    for (int k = 0; k < 16; ++k) red[grp][lane * 16 + k] = acc[k];
    __syncthreads();
    // combine 8 groups per graph, write 4 part rows
    for (int i = tid; i < GPB * HID; i += 256) {
        int gg = i >> 7, f = i & 127;
        int rb = gg * 8;
        float s = 0.f;
#pragma unroll
        for (int r = 0; r < 8; ++r) s += red[rb + r][f];
        part[(size_t)((gset * GPB + gg) * NREG + p) * HID + f] = s;
    }
}

// ---------------- combine partials + mean + W2 + b2 + head ----------------
__global__ void combine_head(const float* __restrict__ part, const int* __restrict__ gb,
                             const float* __restrict__ W2, const float* __restrict__ b2,
                             const float* __restrict__ Wlin, const float* __restrict__ blin,
                             float* __restrict__ out) {
    __shared__ float r[HID];
    __shared__ float tt[HID];
    int g = blockIdx.x;
    int f = threadIdx.x;                 // 0..127
    float s = 0.f;
#pragma unroll
    for (int p = 0; p < NREG; ++p) s += part[(size_t)(g * NREG + p) * HID + f];
    int cnt = gb[g + 1] - gb[g];
    float inv = (cnt > 0) ? 1.0f / (float)cnt : 0.f;
    r[f] = s * inv;
    __syncthreads();
    float bs = (cnt > 0) ? 1.0f : 0.f;
    float tj = b2[f] * bs;
#pragma unroll 8
    for (int k = 0; k < HID; ++k) tj += r[k] * W2[k * HID + f];
    tt[f] = tj;
    __syncthreads();
    if (f < F_OUT) {
        float o = blin[f];
#pragma unroll 8
        for (int k = 0; k < HID; ++k) o += tt[k] * Wlin[k * F_OUT + f];
        out[(size_t)g * F_OUT + f] = o;
    }
}

extern "C" void kernel_launch(void* const* d_in, const int* in_sizes, int n_in,
                              void* d_out, int out_size, void* d_ws, size_t ws_size,
                              hipStream_t stream) {
    const float* x    = (const float*)d_in[0];
    const int*   esrc = (const int*)  d_in[1];
    const int*   edst = (const int*)  d_in[2];
    const int*   batch= (const int*)  d_in[3];
    const float* W1   = (const float*)d_in[4];
    const float* b1   = (const float*)d_in[5];
    const float* W2   = (const float*)d_in[6];
    const float* b2   = (const float*)d_in[7];
    const float* Wlin = (const float*)d_in[8];
    const float* blin = (const float*)d_in[9];
    float* out = (float*)d_out;

    // workspace layout (~106 MB), 16B-aligned segments
    char* p = (char*)d_ws;
    float*        dinv    = (float*)p;        p += sizeof(float) * N_NODES;
    __half*       xp      = (__half*)p;       p += sizeof(__half) * (size_t)N_NODES * F_PAD;
    __half*       Bh      = (__half*)p;       p += sizeof(__half) * (size_t)N_NODES * HID;
    unsigned int* ebuf    = (unsigned int*)p; p += sizeof(unsigned int) * (size_t)NB * BCAP;
    int*          col     = (int*)p;          p += sizeof(int) * (size_t)NB * BCAP;
    float*        wd      = (float*)p;        p += sizeof(float) * (size_t)NB * BCAP;
    int*          deg     = (int*)p;          p += sizeof(int) * N_NODES;
    uint2*        ewp     = (uint2*)p;        p += sizeof(uint2) * (size_t)NUM_G * GCAP;
    float*        part    = (float*)p;        p += sizeof(float) * (size_t)NUM_G * NREG * HID;
    int*          row_ptr = (int*)p;          p += sizeof(int) * (N_NODES + 4);
    int*          gb      = (int*)p;          p += sizeof(int) * (NUM_G + 4);
    int*          gro     = (int*)p;          p += sizeof(int) * (NUM_G * 9 + 4);
    int*          bcur    = (int*)p;          p += sizeof(int) * NB;

    const int nblk_e = (N_EDGES + P01_EPB - 1) / P01_EPB;   // 782

    // ---- single-pass padded counting sort + CSR + dinv + wd + xp ----
    hipMemsetAsync(bcur, 0, sizeof(int) * NB, stream);
    p1_place<<<nblk_e, 256, 0, stream>>>(esrc, edst, bcur, ebuf);
    p2_build<<<NB, 512, 0, stream>>>(ebuf, bcur, x, row_ptr, deg, col, wd, dinv, xp);

    // ---- fused: layer-1 aggregate + W1-GEMM (blocks 0..781)
    //            + per-graph region sort (blocks 782..4877) — independent, co-scheduled
    agg_es8<<<NAGG + NUM_G, 256, 0, stream>>>(xp, row_ptr, deg, col, dinv, W1, b1, Bh,
                                              batch, wd, ewp, gro, gb);

    // ---- XCD-sharded layer-2 aggregate + pool partials (4 graphs/block) ----
    pool_gather<<<(NUM_G / GPB) * NREG, 256, 0, stream>>>(Bh, gro, ewp, part);

    // ---- combine + mean + W2 + b2 + Wlin + blin ----
    combine_head<<<NUM_G, HID, 0, stream>>>(part, gb, W2, b2, Wlin, blin, out);
}